// Round 10
// baseline (323.012 us; speedup 1.0000x reference)
//
#include <hip/hip_runtime.h>
#include <math.h>

#define B_SZ   32
#define C_DIM  384
#define H_IN   28
#define W_IN   28
#define TQ     785   // 1 + 28*28
#define TKV    197   // 1 + 14*14
#define NH     6
#define HD     64
#define SCALE_F 0.05103103630798287f       // 384^-0.5
#define SCALE_L2E (0.05103103630798287f * 1.4426950408889634f)  // fold log2(e)
#define BN_EPS_F 1e-5f

#define QROWS    25120        // B_SZ*TQ
#define KVROWS   6304         // B_SZ*TKV
#define QROWS_P  25216        // = 128*197
#define KVROWS_P 6400         // = 128*50
#define WELEM    147456       // 384*384
#define VT_LD    208          // V^T key stride (16B-aligned rows, >= 197)

#define QTILES   197          // QROWS_P/128
#define KVTILES  50           // KVROWS_P/128

typedef _Float16 f16;
typedef f16  f16x8 __attribute__((ext_vector_type(8)));
typedef f16  f16x4 __attribute__((ext_vector_type(4)));
typedef float f32x4 __attribute__((ext_vector_type(4)));

__device__ __forceinline__ void split16(float v, f16& h, f16& l) {
    h = (f16)v;
    l = (f16)(v - (float)h);
}

// async global->LDS DMA, 16 B per lane. HW writes at wave-uniform base +
// lane*16 -- every call site below computes LDS offset == idx*16 with idx
// affine in threadIdx (lane-stride exactly 16 B).
__device__ __forceinline__ void cp16(void* lds, const void* g) {
    __builtin_amdgcn_global_load_lds(
        (const __attribute__((address_space(1))) unsigned int*)g,
        (__attribute__((address_space(3))) unsigned int*)lds, 16, 0, 0);
}

// ---------------- prep: weight decompose (+scale fold into w_q) + conv/BN fold --
__global__ __launch_bounds__(256) void prep_kernel(
    const float* __restrict__ wq, const float* __restrict__ wk,
    const float* __restrict__ wv, const float* __restrict__ wp,
    const float* __restrict__ conv_w,
    const float* __restrict__ gamma, const float* __restrict__ beta,
    const float* __restrict__ mean, const float* __restrict__ var,
    f16* __restrict__ Wh, f16* __restrict__ Wl,
    float* __restrict__ wAll)
{
    int idx = blockIdx.x * 256 + threadIdx.x;
    if (idx < 4 * WELEM) {
        int which = idx / WELEM, rem = idx - which * WELEM;
        const float* s = (which == 0) ? wq : (which == 1) ? wk : (which == 2) ? wv : wp;
        float v = s[rem];
        if (which == 0) v *= SCALE_L2E;   // QK^T logits in log2 domain
        f16 h, l;
        split16(v, h, l);
        Wh[idx] = h; Wl[idx] = l;
    } else if (idx < 4 * WELEM + 3 * C_DIM) {
        int k = idx - 4 * WELEM;
        int cv = k / C_DIM, c = k - cv * C_DIM;
        float inv = gamma[k] * rsqrtf(var[k] + BN_EPS_F);
#pragma unroll
        for (int t = 0; t < 9; ++t)
            wAll[cv * 3840 + t * C_DIM + c] = conv_w[(size_t)cv * C_DIM * 9 + c * 9 + t] * inv;
        wAll[cv * 3840 + 9 * C_DIM + c] = beta[k] - mean[k] * inv;
    }
}

// ---------------- fused depthwise conv (Q stride1 + K/V stride2) + cls row -----
__global__ __launch_bounds__(256) void fused_conv_kernel(
    const float* __restrict__ x,
    const float* __restrict__ wAll,
    f16* __restrict__ qh, f16* __restrict__ ql,
    f16* __restrict__ kh, f16* __restrict__ kl,
    f16* __restrict__ vh, f16* __restrict__ vl)
{
    __shared__ float sW[3 * 3840];
    int tid = threadIdx.x;
    int oi = blockIdx.x, b = blockIdx.y;

    if (oi == H_IN) {                 // cls-token path
        if (tid < 96) {
            int c = tid * 4;
            float4 v = *(const float4*)&x[(size_t)b * TQ * C_DIM + c];
            float a[4] = {v.x, v.y, v.z, v.w};
            f16x4 hv, lv;
#pragma unroll
            for (int u = 0; u < 4; ++u) { f16 h, l; split16(a[u], h, l); hv[u] = h; lv[u] = l; }
            size_t oq = (size_t)b * TQ * C_DIM + c;
            size_t okv = (size_t)b * TKV * C_DIM + c;
            *(f16x4*)&qh[oq] = hv;  *(f16x4*)&ql[oq] = lv;
            *(f16x4*)&kh[okv] = hv; *(f16x4*)&kl[okv] = lv;
            *(f16x4*)&vh[okv] = hv; *(f16x4*)&vl[okv] = lv;
        }
        return;
    }

#pragma unroll
    for (int i = 0; i < 12; ++i) {
        int idx = tid + 256 * i;
        if (idx < 2880) cp16(&sW[idx * 4], &wAll[idx * 4]);
    }
    __syncthreads();

    const size_t xb = (size_t)b * TQ * C_DIM + C_DIM;
    bool oi_even = (oi & 1) == 0;

    for (int it = 0; it < 11; ++it) {
        int idx = tid + 256 * it;
        if (idx >= 28 * 96) break;
        int oj = idx / 96, cg = idx - oj * 96;
        int c = cg * 4;

        float4 xv[9];
#pragma unroll
        for (int di = 0; di < 3; ++di) {
            int ii = oi + di - 1;
            bool rok = (ii >= 0) && (ii < H_IN);
#pragma unroll
            for (int dj = 0; dj < 3; ++dj) {
                int jj = oj + dj - 1;
                bool ok = rok && (jj >= 0) && (jj < W_IN);
                xv[di * 3 + dj] = ok ? *(const float4*)&x[xb + ((size_t)ii * W_IN + jj) * C_DIM + c]
                                     : make_float4(0.f, 0.f, 0.f, 0.f);
            }
        }

        {
            float4 acc = *(const float4*)&sW[0 * 3840 + 9 * C_DIM + c];
#pragma unroll
            for (int t = 0; t < 9; ++t) {
                float4 w4 = *(const float4*)&sW[0 * 3840 + t * C_DIM + c];
                acc.x += w4.x * xv[t].x; acc.y += w4.y * xv[t].y;
                acc.z += w4.z * xv[t].z; acc.w += w4.w * xv[t].w;
            }
            f16x4 hv, lv;
            float a[4] = {acc.x, acc.y, acc.z, acc.w};
#pragma unroll
            for (int u = 0; u < 4; ++u) { f16 h, l; split16(a[u], h, l); hv[u] = h; lv[u] = l; }
            size_t off = ((size_t)b * TQ + 1 + oi * W_IN + oj) * C_DIM + c;
            *(f16x4*)&qh[off] = hv;
            *(f16x4*)&ql[off] = lv;
        }

        if (oi_even && ((oj & 1) == 0)) {
            int p = (oi >> 1) * 14 + (oj >> 1);
            size_t off = ((size_t)b * TKV + 1 + p) * C_DIM + c;
#pragma unroll
            for (int cv = 1; cv <= 2; ++cv) {
                float4 acc = *(const float4*)&sW[cv * 3840 + 9 * C_DIM + c];
#pragma unroll
                for (int t = 0; t < 9; ++t) {
                    float4 w4 = *(const float4*)&sW[cv * 3840 + t * C_DIM + c];
                    acc.x += w4.x * xv[t].x; acc.y += w4.y * xv[t].y;
                    acc.z += w4.z * xv[t].z; acc.w += w4.w * xv[t].w;
                }
                f16x4 hv, lv;
                float a[4] = {acc.x, acc.y, acc.z, acc.w};
#pragma unroll
                for (int u = 0; u < 4; ++u) { f16 h, l; split16(a[u], h, l); hv[u] = h; lv[u] = l; }
                if (cv == 1) { *(f16x4*)&kh[off] = hv; *(f16x4*)&kl[off] = lv; }
                else         { *(f16x4*)&vh[off] = hv; *(f16x4*)&vl[off] = lv; }
            }
        }
    }
}

// ---------------- split-f16 MFMA GEMM body (128x128 tile, DMA staging) ---------
// 4 waves in 2x2; wave = 64x64 (4x4 MFMA tiles). 192 MFMA per K-step per block.
// Staging: idx = t + 256*i, row = idx>>2, sg = (idx&3)*8 -> LDS offset idx*16
// (lane-stride 16 B, required by global_load_lds).
__device__ __forceinline__ void gemm_body(
    const f16* __restrict__ Ah, const f16* __restrict__ Al,
    const f16* __restrict__ Wh, const f16* __restrict__ Wl,
    const float* __restrict__ bias,
    float* __restrict__ Cf, f16* __restrict__ Coh, f16* __restrict__ Col,
    int M, int mode, int m0, int n0)
{
    __shared__ f16 sAh[128][32];
    __shared__ f16 sAl[128][32];
    __shared__ f16 sWh[128][32];
    __shared__ f16 sWl[128][32];

    int t = threadIdx.x;
    int wv = t >> 6, lane = t & 63;
    int wr = (wv >> 1) * 64, wc = (wv & 1) * 64;
    int lrow = lane & 15, quad = lane >> 4;

    f32x4 acc[4][4];
#pragma unroll
    for (int i = 0; i < 4; ++i)
#pragma unroll
        for (int j = 0; j < 4; ++j)
            acc[i][j] = (f32x4){0.f, 0.f, 0.f, 0.f};

    for (int k0 = 0; k0 < 384; k0 += 32) {
        __syncthreads();
#pragma unroll
        for (int i = 0; i < 2; ++i) {
            int idx = t + 256 * i;
            int row = idx >> 2, sg = (idx & 3) * 8;
            cp16(&sAh[row][sg], &Ah[(size_t)(m0 + row) * 384 + k0 + sg]);
            cp16(&sAl[row][sg], &Al[(size_t)(m0 + row) * 384 + k0 + sg]);
            cp16(&sWh[row][sg], &Wh[(size_t)(n0 + row) * 384 + k0 + sg]);
            cp16(&sWl[row][sg], &Wl[(size_t)(n0 + row) * 384 + k0 + sg]);
        }
        __syncthreads();

        f16x8 bh[4], bl[4];
#pragma unroll
        for (int j = 0; j < 4; ++j) {
            bh[j] = *(const f16x8*)&sWh[wc + j * 16 + lrow][quad * 8];
            bl[j] = *(const f16x8*)&sWl[wc + j * 16 + lrow][quad * 8];
        }
#pragma unroll
        for (int i = 0; i < 4; ++i) {
            f16x8 ah = *(const f16x8*)&sAh[wr + i * 16 + lrow][quad * 8];
            f16x8 al = *(const f16x8*)&sAl[wr + i * 16 + lrow][quad * 8];
#pragma unroll
            for (int j = 0; j < 4; ++j) {
                acc[i][j] = __builtin_amdgcn_mfma_f32_16x16x32_f16(ah, bh[j], acc[i][j], 0, 0, 0);
                acc[i][j] = __builtin_amdgcn_mfma_f32_16x16x32_f16(ah, bl[j], acc[i][j], 0, 0, 0);
                acc[i][j] = __builtin_amdgcn_mfma_f32_16x16x32_f16(al, bh[j], acc[i][j], 0, 0, 0);
            }
        }
    }

    // epilogue: C/D layout col=lane&15, row=quad*4+reg
#pragma unroll
    for (int i = 0; i < 4; ++i) {
        int grow0 = m0 + wr + i * 16 + quad * 4;
#pragma unroll
        for (int j = 0; j < 4; ++j) {
            int gcol = n0 + wc + j * 16 + lrow;
            float bb = (bias && mode == 0) ? bias[gcol] : 0.f;
#pragma unroll
            for (int r = 0; r < 4; ++r) {
                int grow = grow0 + r;
                if (grow >= M) continue;
                float v = acc[i][j][r] + bb;
                if (mode == 0) {
                    Cf[(size_t)grow * 384 + gcol] = v;
                } else if (mode == 1) {
                    f16 h, l;
                    split16(v, h, l);
                    Coh[(size_t)grow * 384 + gcol] = h;
                    Col[(size_t)grow * 384 + gcol] = l;
                } else {
                    int bb2 = grow / TKV;
                    int key = grow - bb2 * TKV;
                    size_t off = (size_t)bb2 * 384 * VT_LD + (size_t)gcol * VT_LD + key;
                    f16 h, l;
                    split16(v, h, l);
                    Coh[off] = h;
                    Col[off] = l;
                }
            }
        }
    }
}

// merged Q+K projections (flat y grid, no aliasing hazard between them)
__global__ __launch_bounds__(256) void qk_proj_kernel(
    const f16* __restrict__ qh, const f16* __restrict__ ql,
    const f16* __restrict__ kh, const f16* __restrict__ kl,
    const f16* __restrict__ Wh, const f16* __restrict__ Wl,
    f16* __restrict__ Qph, f16* __restrict__ Qpl,
    f16* __restrict__ Kph, f16* __restrict__ Kpl)
{
    int y = blockIdx.y;
    int n0 = blockIdx.x * 128;
    if (y < QTILES)
        gemm_body(qh, ql, Wh, Wl, nullptr, nullptr, Qph, Qpl, QROWS, 1, y * 128, n0);
    else
        gemm_body(kh, kl, Wh + WELEM, Wl + WELEM, nullptr, nullptr, Kph, Kpl,
                  KVROWS, 1, (y - QTILES) * 128, n0);
}

// V projection, separate launch: VT overlays dead kh/kl + wq/wk-hi, which are
// only dead once qk_proj has fully completed (stream ordering guarantees it).
__global__ __launch_bounds__(256) void v_proj_kernel(
    const f16* __restrict__ vh, const f16* __restrict__ vl,
    const f16* __restrict__ Wh, const f16* __restrict__ Wl,
    f16* __restrict__ VTh, f16* __restrict__ VTl)
{
    gemm_body(vh, vl, Wh, Wl, nullptr, nullptr, VTh, VTl, KVROWS, 2,
              blockIdx.y * 128, blockIdx.x * 128);
}

__global__ __launch_bounds__(256) void out_proj_kernel(
    const f16* __restrict__ Ah, const f16* __restrict__ Al,
    const f16* __restrict__ Wh, const f16* __restrict__ Wl,
    const float* __restrict__ bias, float* __restrict__ Cf)
{
    gemm_body(Ah, Al, Wh, Wl, bias, Cf, nullptr, nullptr, QROWS, 0,
              blockIdx.y * 128, blockIdx.x * 128);
}

// ---------------- MFMA attention v3: non-flash single-pass softmax ----------
__global__ __launch_bounds__(256) void attn_mfma3(
    const f16* __restrict__ Qh, const f16* __restrict__ Ql,
    const f16* __restrict__ Kh, const f16* __restrict__ Kl,
    const f16* __restrict__ VTh, const f16* __restrict__ VTl,
    f16* __restrict__ Oh, f16* __restrict__ Ol)
{
    __shared__ f16 sQh[2][64][32];
    __shared__ f16 sQl[2][64][32];
    __shared__ f16 sKh[2][64][32];
    __shared__ f16 sKl[2][64][32];
    __shared__ float sPs[64][68];

    int t = threadIdx.x;
    int wv = t >> 6, lane = t & 63;
    int c = lane & 15, quad = lane >> 4;
    int wq0 = wv * 16;
    int h = blockIdx.y, b = blockIdx.z;
    int q0 = blockIdx.x * 64;

    const size_t qbase  = (size_t)b * TQ * C_DIM + h * HD;
    const size_t kbase  = (size_t)b * TKV * C_DIM + h * HD;
    const size_t vtbase = (size_t)b * 384 * VT_LD + (size_t)h * HD * VT_LD;

#pragma unroll
    for (int i = 0; i < 2; ++i) {
        int idx = t + 256 * i;
        int ks = idx >> 8, row = (idx >> 2) & 63, sg = (idx & 3) * 8;
        cp16(&sQh[ks][row][sg], &Qh[qbase + (size_t)(q0 + row) * C_DIM + ks * 32 + sg]);
        cp16(&sQl[ks][row][sg], &Ql[qbase + (size_t)(q0 + row) * C_DIM + ks * 32 + sg]);
    }

    f32x4 s[4][4];
#pragma unroll
    for (int kt = 0; kt < 4; ++kt)
#pragma unroll
        for (int j = 0; j < 4; ++j)
            s[kt][j] = (f32x4){0.f, 0.f, 0.f, 0.f};

#pragma unroll
    for (int kt = 0; kt < 4; ++kt) {
        __syncthreads();
#pragma unroll
        for (int i = 0; i < 2; ++i) {
            int idx = t + 256 * i;
            int ks = idx >> 8, row = (idx >> 2) & 63, sg = (idx & 3) * 8;
            cp16(&sKh[ks][row][sg], &Kh[kbase + (size_t)(kt * 64 + row) * C_DIM + ks * 32 + sg]);
            cp16(&sKl[ks][row][sg], &Kl[kbase + (size_t)(kt * 64 + row) * C_DIM + ks * 32 + sg]);
        }
        __syncthreads();

#pragma unroll
        for (int ks = 0; ks < 2; ++ks) {
            f16x8 qh8 = *(const f16x8*)&sQh[ks][wq0 + c][quad * 8];
            f16x8 ql8 = *(const f16x8*)&sQl[ks][wq0 + c][quad * 8];
#pragma unroll
            for (int j = 0; j < 4; ++j) {
                f16x8 kh8 = *(const f16x8*)&sKh[ks][j * 16 + c][quad * 8];
                f16x8 kl8 = *(const f16x8*)&sKl[ks][j * 16 + c][quad * 8];
                s[kt][j] = __builtin_amdgcn_mfma_f32_16x16x32_f16(qh8, kh8, s[kt][j], 0, 0, 0);
                s[kt][j] = __builtin_amdgcn_mfma_f32_16x16x32_f16(qh8, kl8, s[kt][j], 0, 0, 0);
                s[kt][j] = __builtin_amdgcn_mfma_f32_16x16x32_f16(ql8, kh8, s[kt][j], 0, 0, 0);
            }
        }
    }

#pragma unroll
    for (int r = 0; r < 4; ++r) {
        s[3][0][r] = (c < 5) ? s[3][0][r] : -1e30f;
        s[3][1][r] = -1e30f;
        s[3][2][r] = -1e30f;
        s[3][3][r] = -1e30f;
    }

    float inv_r[4];
#pragma unroll
    for (int r = 0; r < 4; ++r) {
        float mx = -1e30f;
#pragma unroll
        for (int kt = 0; kt < 4; ++kt)
#pragma unroll
            for (int j = 0; j < 4; ++j)
                mx = fmaxf(mx, s[kt][j][r]);
        mx = fmaxf(mx, __shfl_xor(mx, 1));
        mx = fmaxf(mx, __shfl_xor(mx, 2));
        mx = fmaxf(mx, __shfl_xor(mx, 4));
        mx = fmaxf(mx, __shfl_xor(mx, 8));
        float sum = 0.f;
#pragma unroll
        for (int kt = 0; kt < 4; ++kt)
#pragma unroll
            for (int j = 0; j < 4; ++j) {
                float pv = exp2f(s[kt][j][r] - mx);
                s[kt][j][r] = pv;
                sum += pv;
            }
        sum += __shfl_xor(sum, 1);
        sum += __shfl_xor(sum, 2);
        sum += __shfl_xor(sum, 4);
        sum += __shfl_xor(sum, 8);
        inv_r[r] = 1.f / sum;
    }

    f32x4 o[4];
#pragma unroll
    for (int j = 0; j < 4; ++j) o[j] = (f32x4){0.f, 0.f, 0.f, 0.f};

#pragma unroll
    for (int vt = 0; vt < 4; ++vt) {
#pragma unroll
        for (int r = 0; r < 4; ++r)
#pragma unroll
            for (int j = 0; j < 4; ++j)
                sPs[wq0 + quad * 4 + r][j * 16 + c] = s[vt][j][r];

        __syncthreads();
#pragma unroll
        for (int i = 0; i < 2; ++i) {
            int idx = t + 256 * i;
            int ks = idx >> 8, row = (idx >> 2) & 63, sg = (idx & 3) * 8;
            cp16(&sKh[ks][row][sg], &VTh[vtbase + (size_t)row * VT_LD + vt * 64 + ks * 32 + sg]);
            cp16(&sKl[ks][row][sg], &VTl[vtbase + (size_t)row * VT_LD + vt * 64 + ks * 32 + sg]);
        }
        __syncthreads();

#pragma unroll
        for (int ks = 0; ks < 2; ++ks) {
            float4 p0 = *(const float4*)&sPs[wq0 + c][ks * 32 + quad * 8];
            float4 p1 = *(const float4*)&sPs[wq0 + c][ks * 32 + quad * 8 + 4];
            float pf[8] = {p0.x, p0.y, p0.z, p0.w, p1.x, p1.y, p1.z, p1.w};
            f16x8 ph8, pl8;
#pragma unroll
            for (int ii = 0; ii < 8; ++ii) {
                f16 hh, ll;
                split16(pf[ii], hh, ll);
                ph8[ii] = hh; pl8[ii] = ll;
            }
#pragma unroll
            for (int j = 0; j < 4; ++j) {
                f16x8 vh8 = *(const f16x8*)&sKh[ks][j * 16 + c][quad * 8];
                f16x8 vl8 = *(const f16x8*)&sKl[ks][j * 16 + c][quad * 8];
                o[j] = __builtin_amdgcn_mfma_f32_16x16x32_f16(ph8, vh8, o[j], 0, 0, 0);
                o[j] = __builtin_amdgcn_mfma_f32_16x16x32_f16(ph8, vl8, o[j], 0, 0, 0);
                o[j] = __builtin_amdgcn_mfma_f32_16x16x32_f16(pl8, vh8, o[j], 0, 0, 0);
            }
        }
    }

#pragma unroll
    for (int r = 0; r < 4; ++r) {
        int gq = q0 + wq0 + quad * 4 + r;
        if (gq >= TQ) continue;
        float inv = inv_r[r];
#pragma unroll
        for (int j = 0; j < 4; ++j) {
            float v = o[j][r] * inv;
            f16 hh, ll;
            split16(v, hh, ll);
            size_t off = (size_t)(b * TQ + gq) * C_DIM + h * HD + j * 16 + c;
            Oh[off] = hh;
            Ol[off] = ll;
        }
    }
}

extern "C" void kernel_launch(void* const* d_in, const int* in_sizes, int n_in,
                              void* d_out, int out_size, void* d_ws, size_t ws_size,
                              hipStream_t stream) {
    const float* x       = (const float*)d_in[0];
    const float* conv_w  = (const float*)d_in[1];
    const float* bn_g    = (const float*)d_in[2];
    const float* bn_b    = (const float*)d_in[3];
    const float* bn_m    = (const float*)d_in[4];
    const float* bn_v    = (const float*)d_in[5];
    const float* w_q     = (const float*)d_in[6];
    const float* w_k     = (const float*)d_in[7];
    const float* w_v     = (const float*)d_in[8];
    const float* w_proj  = (const float*)d_in[9];
    const float* b_proj  = (const float*)d_in[10];
    float* out = (float*)d_out;

    const size_t QSZ  = (size_t)QROWS_P * 384 * sizeof(f16);
    const size_t KVSZ = (size_t)KVROWS_P * 384 * sizeof(f16);
    const size_t WSZ  = 4 * (size_t)WELEM * sizeof(f16);

    char* p = (char*)d_ws;
    f16* qh  = (f16*)p; p += QSZ;
    f16* ql  = (f16*)p; p += QSZ;
    f16* vh  = (f16*)p; p += KVSZ;
    f16* vl  = (f16*)p; p += KVSZ;
    f16* kh  = (f16*)p; p += KVSZ;
    f16* kl  = (f16*)p; p += KVSZ;
    f16* Wh  = (f16*)p; p += WSZ;
    f16* Wl  = (f16*)p; p += WSZ;
    f16* Qph = (f16*)p; p += QSZ;
    f16* Qpl = (f16*)p; p += QSZ;
    f16* Kph = (f16*)p; p += KVSZ;
    f16* Kpl = (f16*)p; p += KVSZ;
    float* wAll = (float*)p; p += 3 * 3840 * sizeof(float);

    f16* VTh = kh;                     // VT overlays dead kh/kl + wq/wk-hi slices
    f16* VTl = VTh + (size_t)B_SZ * 384 * VT_LD;
    f16* oh  = qh;                     // attn out over dead qh/ql
    f16* ol  = ql;

    // 1) prep
    {
        int total = 4 * WELEM + 3 * C_DIM;
        prep_kernel<<<(total + 255) / 256, 256, 0, stream>>>(
            w_q, w_k, w_v, w_proj, conv_w, bn_g, bn_b, bn_m, bn_v, Wh, Wl, wAll);
    }

    // 2) fused conv (Q + K + V + cls)
    {
        dim3 gc(H_IN + 1, B_SZ);
        fused_conv_kernel<<<gc, 256, 0, stream>>>(x, wAll, qh, ql, kh, kl, vh, vl);
    }

    // 3a) merged Q+K projections (741 blocks, no empties, no aliasing)
    {
        dim3 g(3, QTILES + KVTILES);   // (3, 247)
        qk_proj_kernel<<<g, 256, 0, stream>>>(qh, ql, kh, kl, Wh, Wl,
                                              Qph, Qpl, Kph, Kpl);
    }
    // 3b) V projection -> VT (safe: qk_proj completed, kh/kl + wq/wk-hi dead)
    {
        dim3 g(3, KVTILES);            // (3, 50)
        v_proj_kernel<<<g, 256, 0, stream>>>(vh, vl, Wh + 2 * WELEM, Wl + 2 * WELEM,
                                             VTh, VTl);
    }

    // 4) MFMA attention v3 -> oh/ol
    {
        dim3 ga((TQ + 63) / 64, NH, B_SZ);
        attn_mfma3<<<ga, 256, 0, stream>>>(Qph, Qpl, Kph, Kpl, VTh, VTl, oh, ol);
    }

    // 5) output projection + bias -> f32 out
    {
        dim3 gp(3, QTILES);            // (3, 197)
        out_proj_kernel<<<gp, 256, 0, stream>>>(oh, ol, Wh + 3 * WELEM, Wl + 3 * WELEM,
                                                b_proj, out);
    }
}

// Round 11
// 295.855 us; speedup vs baseline: 1.0918x; 1.0918x over previous
//
#include <hip/hip_runtime.h>
#include <math.h>

#define B_SZ   32
#define C_DIM  384
#define H_IN   28
#define W_IN   28
#define TQ     785   // 1 + 28*28
#define TKV    197   // 1 + 14*14
#define NH     6
#define HD     64
#define SCALE_F 0.05103103630798287f       // 384^-0.5
#define SCALE_L2E (0.05103103630798287f * 1.4426950408889634f)  // fold log2(e)
#define BN_EPS_F 1e-5f

#define QROWS    25120        // B_SZ*TQ
#define KVROWS   6304         // B_SZ*TKV
#define QROWS_P  25216
#define KVROWS_P 6400
#define WELEM    147456       // 384*384
#define VT_LD    208          // V^T key stride (16B-aligned rows, >= 197)

#define QT64     394          // QROWS_P/64
#define KVT64    100          // KVROWS_P/64

typedef _Float16 f16;
typedef f16  f16x8 __attribute__((ext_vector_type(8)));
typedef f16  f16x4 __attribute__((ext_vector_type(4)));
typedef float f32x4 __attribute__((ext_vector_type(4)));

__device__ __forceinline__ void split16(float v, f16& h, f16& l) {
    h = (f16)v;
    l = (f16)(v - (float)h);
}

// async global->LDS DMA, 16 B per lane. HW writes at wave-uniform base +
// lane*16 -- every call site computes LDS offset == idx*16 (lane-stride 16 B).
__device__ __forceinline__ void cp16(void* lds, const void* g) {
    __builtin_amdgcn_global_load_lds(
        (const __attribute__((address_space(1))) unsigned int*)g,
        (__attribute__((address_space(3))) unsigned int*)lds, 16, 0, 0);
}

// ---------------- prep: weight decompose (+scale fold into w_q) + conv/BN fold --
__global__ __launch_bounds__(256) void prep_kernel(
    const float* __restrict__ wq, const float* __restrict__ wk,
    const float* __restrict__ wv, const float* __restrict__ wp,
    const float* __restrict__ conv_w,
    const float* __restrict__ gamma, const float* __restrict__ beta,
    const float* __restrict__ mean, const float* __restrict__ var,
    f16* __restrict__ Wh, f16* __restrict__ Wl,
    float* __restrict__ wAll)
{
    int idx = blockIdx.x * 256 + threadIdx.x;
    if (idx < 4 * WELEM) {
        int which = idx / WELEM, rem = idx - which * WELEM;
        const float* s = (which == 0) ? wq : (which == 1) ? wk : (which == 2) ? wv : wp;
        float v = s[rem];
        if (which == 0) v *= SCALE_L2E;   // QK^T logits in log2 domain
        f16 h, l;
        split16(v, h, l);
        Wh[idx] = h; Wl[idx] = l;
    } else if (idx < 4 * WELEM + 3 * C_DIM) {
        int k = idx - 4 * WELEM;
        int cv = k / C_DIM, c = k - cv * C_DIM;
        float inv = gamma[k] * rsqrtf(var[k] + BN_EPS_F);
#pragma unroll
        for (int t = 0; t < 9; ++t)
            wAll[cv * 3840 + t * C_DIM + c] = conv_w[(size_t)cv * C_DIM * 9 + c * 9 + t] * inv;
        wAll[cv * 3840 + 9 * C_DIM + c] = beta[k] - mean[k] * inv;
    }
}

// ---------------- fused depthwise conv (Q stride1 + K/V stride2) + cls row -----
__global__ __launch_bounds__(256) void fused_conv_kernel(
    const float* __restrict__ x,
    const float* __restrict__ wAll,
    f16* __restrict__ qh, f16* __restrict__ ql,
    f16* __restrict__ kh, f16* __restrict__ kl,
    f16* __restrict__ vh, f16* __restrict__ vl)
{
    __shared__ float sW[3 * 3840];
    int tid = threadIdx.x;
    int oi = blockIdx.x, b = blockIdx.y;

    if (oi == H_IN) {                 // cls-token path
        if (tid < 96) {
            int c = tid * 4;
            float4 v = *(const float4*)&x[(size_t)b * TQ * C_DIM + c];
            float a[4] = {v.x, v.y, v.z, v.w};
            f16x4 hv, lv;
#pragma unroll
            for (int u = 0; u < 4; ++u) { f16 h, l; split16(a[u], h, l); hv[u] = h; lv[u] = l; }
            size_t oq = (size_t)b * TQ * C_DIM + c;
            size_t okv = (size_t)b * TKV * C_DIM + c;
            *(f16x4*)&qh[oq] = hv;  *(f16x4*)&ql[oq] = lv;
            *(f16x4*)&kh[okv] = hv; *(f16x4*)&kl[okv] = lv;
            *(f16x4*)&vh[okv] = hv; *(f16x4*)&vl[okv] = lv;
        }
        return;
    }

#pragma unroll
    for (int i = 0; i < 12; ++i) {
        int idx = tid + 256 * i;
        if (idx < 2880) cp16(&sW[idx * 4], &wAll[idx * 4]);
    }
    __syncthreads();

    const size_t xb = (size_t)b * TQ * C_DIM + C_DIM;
    bool oi_even = (oi & 1) == 0;

    for (int it = 0; it < 11; ++it) {
        int idx = tid + 256 * it;
        if (idx >= 28 * 96) break;
        int oj = idx / 96, cg = idx - oj * 96;
        int c = cg * 4;

        float4 xv[9];
#pragma unroll
        for (int di = 0; di < 3; ++di) {
            int ii = oi + di - 1;
            bool rok = (ii >= 0) && (ii < H_IN);
#pragma unroll
            for (int dj = 0; dj < 3; ++dj) {
                int jj = oj + dj - 1;
                bool ok = rok && (jj >= 0) && (jj < W_IN);
                xv[di * 3 + dj] = ok ? *(const float4*)&x[xb + ((size_t)ii * W_IN + jj) * C_DIM + c]
                                     : make_float4(0.f, 0.f, 0.f, 0.f);
            }
        }

        {
            float4 acc = *(const float4*)&sW[0 * 3840 + 9 * C_DIM + c];
#pragma unroll
            for (int t = 0; t < 9; ++t) {
                float4 w4 = *(const float4*)&sW[0 * 3840 + t * C_DIM + c];
                acc.x += w4.x * xv[t].x; acc.y += w4.y * xv[t].y;
                acc.z += w4.z * xv[t].z; acc.w += w4.w * xv[t].w;
            }
            f16x4 hv, lv;
            float a[4] = {acc.x, acc.y, acc.z, acc.w};
#pragma unroll
            for (int u = 0; u < 4; ++u) { f16 h, l; split16(a[u], h, l); hv[u] = h; lv[u] = l; }
            size_t off = ((size_t)b * TQ + 1 + oi * W_IN + oj) * C_DIM + c;
            *(f16x4*)&qh[off] = hv;
            *(f16x4*)&ql[off] = lv;
        }

        if (oi_even && ((oj & 1) == 0)) {
            int p = (oi >> 1) * 14 + (oj >> 1);
            size_t off = ((size_t)b * TKV + 1 + p) * C_DIM + c;
#pragma unroll
            for (int cv = 1; cv <= 2; ++cv) {
                float4 acc = *(const float4*)&sW[cv * 3840 + 9 * C_DIM + c];
#pragma unroll
                for (int t = 0; t < 9; ++t) {
                    float4 w4 = *(const float4*)&sW[cv * 3840 + t * C_DIM + c];
                    acc.x += w4.x * xv[t].x; acc.y += w4.y * xv[t].y;
                    acc.z += w4.z * xv[t].z; acc.w += w4.w * xv[t].w;
                }
                f16x4 hv, lv;
                float a[4] = {acc.x, acc.y, acc.z, acc.w};
#pragma unroll
                for (int u = 0; u < 4; ++u) { f16 h, l; split16(a[u], h, l); hv[u] = h; lv[u] = l; }
                if (cv == 1) { *(f16x4*)&kh[off] = hv; *(f16x4*)&kl[off] = lv; }
                else         { *(f16x4*)&vh[off] = hv; *(f16x4*)&vl[off] = lv; }
            }
        }
    }
}

// ---------------- split-f16 MFMA GEMM body (64x128 tile, DMA staging) ----------
// R8-proven: 4 waves 2x2; wave = 32x64 (2x4 MFMA tiles); 6 cp16/thread/K-step,
// LDS offsets all == t*16 (lane-contiguous).
__device__ __forceinline__ void gemm_body(
    const f16* __restrict__ Ah, const f16* __restrict__ Al,
    const f16* __restrict__ Wh, const f16* __restrict__ Wl,
    const float* __restrict__ bias,
    float* __restrict__ Cf, f16* __restrict__ Coh, f16* __restrict__ Col,
    int M, int mode, int m0, int n0)
{
    __shared__ f16 sAh[64][32];
    __shared__ f16 sAl[64][32];
    __shared__ f16 sWh[128][32];
    __shared__ f16 sWl[128][32];

    int t = threadIdx.x;
    int wv = t >> 6, lane = t & 63;
    int wr = (wv >> 1) * 32, wc = (wv & 1) * 64;
    int lrow = lane & 15, quad = lane >> 4;
    int arow = t >> 2;
    int aseg = (t & 3) * 8;

    f32x4 acc[2][4];
#pragma unroll
    for (int i = 0; i < 2; ++i)
#pragma unroll
        for (int j = 0; j < 4; ++j)
            acc[i][j] = (f32x4){0.f, 0.f, 0.f, 0.f};

    for (int k0 = 0; k0 < 384; k0 += 32) {
        __syncthreads();
        cp16(&sAh[arow][aseg],      &Ah[(size_t)(m0 + arow) * 384 + k0 + aseg]);
        cp16(&sAl[arow][aseg],      &Al[(size_t)(m0 + arow) * 384 + k0 + aseg]);
        cp16(&sWh[arow][aseg],      &Wh[(size_t)(n0 + arow) * 384 + k0 + aseg]);
        cp16(&sWh[arow + 64][aseg], &Wh[(size_t)(n0 + arow + 64) * 384 + k0 + aseg]);
        cp16(&sWl[arow][aseg],      &Wl[(size_t)(n0 + arow) * 384 + k0 + aseg]);
        cp16(&sWl[arow + 64][aseg], &Wl[(size_t)(n0 + arow + 64) * 384 + k0 + aseg]);
        __syncthreads();

        f16x8 bh[4], bl[4];
#pragma unroll
        for (int j = 0; j < 4; ++j) {
            bh[j] = *(const f16x8*)&sWh[wc + j * 16 + lrow][quad * 8];
            bl[j] = *(const f16x8*)&sWl[wc + j * 16 + lrow][quad * 8];
        }
#pragma unroll
        for (int i = 0; i < 2; ++i) {
            f16x8 ah = *(const f16x8*)&sAh[wr + i * 16 + lrow][quad * 8];
            f16x8 al = *(const f16x8*)&sAl[wr + i * 16 + lrow][quad * 8];
#pragma unroll
            for (int j = 0; j < 4; ++j) {
                acc[i][j] = __builtin_amdgcn_mfma_f32_16x16x32_f16(ah, bh[j], acc[i][j], 0, 0, 0);
                acc[i][j] = __builtin_amdgcn_mfma_f32_16x16x32_f16(ah, bl[j], acc[i][j], 0, 0, 0);
                acc[i][j] = __builtin_amdgcn_mfma_f32_16x16x32_f16(al, bh[j], acc[i][j], 0, 0, 0);
            }
        }
    }

    // epilogue: C/D layout col=lane&15, row=quad*4+reg
#pragma unroll
    for (int i = 0; i < 2; ++i) {
        int grow0 = m0 + wr + i * 16 + quad * 4;
#pragma unroll
        for (int j = 0; j < 4; ++j) {
            int gcol = n0 + wc + j * 16 + lrow;
            float bb = (bias && mode == 0) ? bias[gcol] : 0.f;
#pragma unroll
            for (int r = 0; r < 4; ++r) {
                int grow = grow0 + r;
                if (grow >= M) continue;
                float v = acc[i][j][r] + bb;
                if (mode == 0) {
                    Cf[(size_t)grow * 384 + gcol] = v;
                } else if (mode == 1) {
                    f16 h, l;
                    split16(v, h, l);
                    Coh[(size_t)grow * 384 + gcol] = h;
                    Col[(size_t)grow * 384 + gcol] = l;
                } else {
                    int bb2 = grow / TKV;
                    int key = grow - bb2 * TKV;
                    size_t off = (size_t)bb2 * 384 * VT_LD + (size_t)gcol * VT_LD + key;
                    f16 h, l;
                    split16(v, h, l);
                    Coh[off] = h;
                    Col[off] = l;
                }
            }
        }
    }
}

// Q/K/V projections. Launch y-extent decides coverage:
//  y in [0,394) Q-tiles, [394,494) K-tiles, [494,594) V-tiles.
// Merged launch (y=594) requires VT to be a NON-aliased buffer.
__global__ __launch_bounds__(256) void qkv_proj_kernel(
    const f16* __restrict__ qh, const f16* __restrict__ ql,
    const f16* __restrict__ kh, const f16* __restrict__ kl,
    const f16* __restrict__ vh, const f16* __restrict__ vl,
    const f16* __restrict__ Wh, const f16* __restrict__ Wl,
    f16* __restrict__ Qph, f16* __restrict__ Qpl,
    f16* __restrict__ Kph, f16* __restrict__ Kpl,
    f16* __restrict__ VTh, f16* __restrict__ VTl)
{
    int y = blockIdx.y;
    int n0 = blockIdx.x * 128;
    if (y < QT64)
        gemm_body(qh, ql, Wh, Wl, nullptr, nullptr, Qph, Qpl, QROWS, 1, y * 64, n0);
    else if (y < QT64 + KVT64)
        gemm_body(kh, kl, Wh + WELEM, Wl + WELEM, nullptr, nullptr, Kph, Kpl,
                  KVROWS, 1, (y - QT64) * 64, n0);
    else
        gemm_body(vh, vl, Wh + 2 * WELEM, Wl + 2 * WELEM, nullptr, nullptr, VTh, VTl,
                  KVROWS, 2, (y - QT64 - KVT64) * 64, n0);
}

// fallback V projection (aliased-VT workspace layout)
__global__ __launch_bounds__(256) void v_proj_kernel(
    const f16* __restrict__ vh, const f16* __restrict__ vl,
    const f16* __restrict__ Wh, const f16* __restrict__ Wl,
    f16* __restrict__ VTh, f16* __restrict__ VTl)
{
    gemm_body(vh, vl, Wh, Wl, nullptr, nullptr, VTh, VTl, KVROWS, 2,
              blockIdx.y * 64, blockIdx.x * 128);
}

__global__ __launch_bounds__(256) void out_proj_kernel(
    const f16* __restrict__ Ah, const f16* __restrict__ Al,
    const f16* __restrict__ Wh, const f16* __restrict__ Wl,
    const float* __restrict__ bias, float* __restrict__ Cf)
{
    gemm_body(Ah, Al, Wh, Wl, bias, Cf, nullptr, nullptr, QROWS, 0,
              blockIdx.y * 64, blockIdx.x * 128);
}

// ---------------- MFMA attention v4: single-pass softmax + hidden DMA ----------
__global__ __launch_bounds__(256) void attn_mfma4(
    const f16* __restrict__ Qh, const f16* __restrict__ Ql,
    const f16* __restrict__ Kh, const f16* __restrict__ Kl,
    const f16* __restrict__ VTh, const f16* __restrict__ VTl,
    f16* __restrict__ Oh, f16* __restrict__ Ol)
{
    __shared__ f16 sQh[2][64][32];
    __shared__ f16 sQl[2][64][32];
    __shared__ f16 sKh[2][64][32];
    __shared__ f16 sKl[2][64][32];
    __shared__ float sPs[64][68];

    int t = threadIdx.x;
    int wv = t >> 6, lane = t & 63;
    int c = lane & 15, quad = lane >> 4;
    int wq0 = wv * 16;
    int h = blockIdx.y, b = blockIdx.z;
    int q0 = blockIdx.x * 64;

    const size_t qbase  = (size_t)b * TQ * C_DIM + h * HD;
    const size_t kbase  = (size_t)b * TKV * C_DIM + h * HD;
    const size_t vtbase = (size_t)b * 384 * VT_LD + (size_t)h * HD * VT_LD;

    // stage Q tile (drained by first K-round barrier)
#pragma unroll
    for (int i = 0; i < 2; ++i) {
        int idx = t + 256 * i;
        int ks = idx >> 8, row = (idx >> 2) & 63, sg = (idx & 3) * 8;
        cp16(&sQh[ks][row][sg], &Qh[qbase + (size_t)(q0 + row) * C_DIM + ks * 32 + sg]);
        cp16(&sQl[ks][row][sg], &Ql[qbase + (size_t)(q0 + row) * C_DIM + ks * 32 + sg]);
    }

    f32x4 s[4][4];
#pragma unroll
    for (int kt = 0; kt < 4; ++kt)
#pragma unroll
        for (int j = 0; j < 4; ++j)
            s[kt][j] = (f32x4){0.f, 0.f, 0.f, 0.f};

    // ---- phase 1: all S tiles ----
#pragma unroll
    for (int kt = 0; kt < 4; ++kt) {
        if (kt) __syncthreads();       // prev K-panel frag reads done
#pragma unroll
        for (int i = 0; i < 2; ++i) {
            int idx = t + 256 * i;
            int ks = idx >> 8, row = (idx >> 2) & 63, sg = (idx & 3) * 8;
            cp16(&sKh[ks][row][sg], &Kh[kbase + (size_t)(kt * 64 + row) * C_DIM + ks * 32 + sg]);
            cp16(&sKl[ks][row][sg], &Kl[kbase + (size_t)(kt * 64 + row) * C_DIM + ks * 32 + sg]);
        }
        __syncthreads();               // drains DMA (incl. Q on first iter)

#pragma unroll
        for (int ks = 0; ks < 2; ++ks) {
            f16x8 qh8 = *(const f16x8*)&sQh[ks][wq0 + c][quad * 8];
            f16x8 ql8 = *(const f16x8*)&sQl[ks][wq0 + c][quad * 8];
#pragma unroll
            for (int j = 0; j < 4; ++j) {
                f16x8 kh8 = *(const f16x8*)&sKh[ks][j * 16 + c][quad * 8];
                f16x8 kl8 = *(const f16x8*)&sKl[ks][j * 16 + c][quad * 8];
                s[kt][j] = __builtin_amdgcn_mfma_f32_16x16x32_f16(qh8, kh8, s[kt][j], 0, 0, 0);
                s[kt][j] = __builtin_amdgcn_mfma_f32_16x16x32_f16(qh8, kl8, s[kt][j], 0, 0, 0);
                s[kt][j] = __builtin_amdgcn_mfma_f32_16x16x32_f16(ql8, kh8, s[kt][j], 0, 0, 0);
            }
        }
    }

    __syncthreads();                   // all S frag reads done: K panels free

    // issue VT tile 0 DMA now -- it rides under the softmax VALU below
#pragma unroll
    for (int i = 0; i < 2; ++i) {
        int idx = t + 256 * i;
        int ks = idx >> 8, row = (idx >> 2) & 63, sg = (idx & 3) * 8;
        cp16(&sKh[ks][row][sg], &VTh[vtbase + (size_t)row * VT_LD + 0 * 64 + ks * 32 + sg]);
        cp16(&sKl[ks][row][sg], &VTl[vtbase + (size_t)row * VT_LD + 0 * 64 + ks * 32 + sg]);
    }

    // ---- phase 2: mask tail + single softmax pass (log2 domain) ----
#pragma unroll
    for (int r = 0; r < 4; ++r) {
        s[3][0][r] = (c < 5) ? s[3][0][r] : -1e30f;  // keys 192..196 valid
        s[3][1][r] = -1e30f;
        s[3][2][r] = -1e30f;
        s[3][3][r] = -1e30f;
    }

    float inv_r[4];
#pragma unroll
    for (int r = 0; r < 4; ++r) {
        float mx = -1e30f;
#pragma unroll
        for (int kt = 0; kt < 4; ++kt)
#pragma unroll
            for (int j = 0; j < 4; ++j)
                mx = fmaxf(mx, s[kt][j][r]);
        mx = fmaxf(mx, __shfl_xor(mx, 1));
        mx = fmaxf(mx, __shfl_xor(mx, 2));
        mx = fmaxf(mx, __shfl_xor(mx, 4));
        mx = fmaxf(mx, __shfl_xor(mx, 8));
        float sum = 0.f;
#pragma unroll
        for (int kt = 0; kt < 4; ++kt)
#pragma unroll
            for (int j = 0; j < 4; ++j) {
                float pv = exp2f(s[kt][j][r] - mx);
                s[kt][j][r] = pv;
                sum += pv;
            }
        sum += __shfl_xor(sum, 1);
        sum += __shfl_xor(sum, 2);
        sum += __shfl_xor(sum, 4);
        sum += __shfl_xor(sum, 8);
        inv_r[r] = 1.f / sum;
    }

    // ---- phase 3: O = P V; DMA for vt+1 issued right after PV(vt) barrier ----
    f32x4 o[4];
#pragma unroll
    for (int j = 0; j < 4; ++j) o[j] = (f32x4){0.f, 0.f, 0.f, 0.f};

#pragma unroll
    for (int vt = 0; vt < 4; ++vt) {
        // write this wave's P strip (wave-private rows); DMA(vt) is in flight
#pragma unroll
        for (int r = 0; r < 4; ++r)
#pragma unroll
            for (int j = 0; j < 4; ++j)
                sPs[wq0 + quad * 4 + r][j * 16 + c] = s[vt][j][r];

        __syncthreads();               // drains DMA(vt); sPs visible

#pragma unroll
        for (int ks = 0; ks < 2; ++ks) {
            float4 p0 = *(const float4*)&sPs[wq0 + c][ks * 32 + quad * 8];
            float4 p1 = *(const float4*)&sPs[wq0 + c][ks * 32 + quad * 8 + 4];
            float pf[8] = {p0.x, p0.y, p0.z, p0.w, p1.x, p1.y, p1.z, p1.w};
            f16x8 ph8, pl8;
#pragma unroll
            for (int ii = 0; ii < 8; ++ii) {
                f16 hh, ll;
                split16(pf[ii], hh, ll);
                ph8[ii] = hh; pl8[ii] = ll;
            }
#pragma unroll
            for (int j = 0; j < 4; ++j) {
                f16x8 vh8 = *(const f16x8*)&sKh[ks][j * 16 + c][quad * 8];
                f16x8 vl8 = *(const f16x8*)&sKl[ks][j * 16 + c][quad * 8];
                o[j] = __builtin_amdgcn_mfma_f32_16x16x32_f16(ph8, vh8, o[j], 0, 0, 0);
                o[j] = __builtin_amdgcn_mfma_f32_16x16x32_f16(ph8, vl8, o[j], 0, 0, 0);
                o[j] = __builtin_amdgcn_mfma_f32_16x16x32_f16(pl8, vh8, o[j], 0, 0, 0);
            }
        }

        if (vt < 3) {
            __syncthreads();           // PV(vt) frag reads done: panels free
#pragma unroll
            for (int i = 0; i < 2; ++i) {
                int idx = t + 256 * i;
                int ks = idx >> 8, row = (idx >> 2) & 63, sg = (idx & 3) * 8;
                cp16(&sKh[ks][row][sg],
                     &VTh[vtbase + (size_t)row * VT_LD + (vt + 1) * 64 + ks * 32 + sg]);
                cp16(&sKl[ks][row][sg],
                     &VTl[vtbase + (size_t)row * VT_LD + (vt + 1) * 64 + ks * 32 + sg]);
            }
            // DMA rides under next iteration's P stores
        }
    }

    // epilogue: normalize, split to f16 hi/lo, store
#pragma unroll
    for (int r = 0; r < 4; ++r) {
        int gq = q0 + wq0 + quad * 4 + r;
        if (gq >= TQ) continue;
        float inv = inv_r[r];
#pragma unroll
        for (int j = 0; j < 4; ++j) {
            float v = o[j][r] * inv;
            f16 hh, ll;
            split16(v, hh, ll);
            size_t off = (size_t)(b * TQ + gq) * C_DIM + h * HD + j * 16 + c;
            Oh[off] = hh;
            Ol[off] = ll;
        }
    }
}

extern "C" void kernel_launch(void* const* d_in, const int* in_sizes, int n_in,
                              void* d_out, int out_size, void* d_ws, size_t ws_size,
                              hipStream_t stream) {
    const float* x       = (const float*)d_in[0];
    const float* conv_w  = (const float*)d_in[1];
    const float* bn_g    = (const float*)d_in[2];
    const float* bn_b    = (const float*)d_in[3];
    const float* bn_m    = (const float*)d_in[4];
    const float* bn_v    = (const float*)d_in[5];
    const float* w_q     = (const float*)d_in[6];
    const float* w_k     = (const float*)d_in[7];
    const float* w_v     = (const float*)d_in[8];
    const float* w_proj  = (const float*)d_in[9];
    const float* b_proj  = (const float*)d_in[10];
    float* out = (float*)d_out;

    const size_t QSZ   = (size_t)QROWS_P * 384 * sizeof(f16);
    const size_t KVSZ  = (size_t)KVROWS_P * 384 * sizeof(f16);
    const size_t WSZ   = 4 * (size_t)WELEM * sizeof(f16);
    const size_t VTSZ  = (size_t)B_SZ * 384 * VT_LD * sizeof(f16);
    const size_t WALLS = 3 * 3840 * sizeof(float);

    char* p = (char*)d_ws;
    f16* qh  = (f16*)p; p += QSZ;
    f16* ql  = (f16*)p; p += QSZ;
    f16* vh  = (f16*)p; p += KVSZ;
    f16* vl  = (f16*)p; p += KVSZ;
    f16* kh  = (f16*)p; p += KVSZ;
    f16* kl  = (f16*)p; p += KVSZ;
    f16* Wh  = (f16*)p; p += WSZ;
    f16* Wl  = (f16*)p; p += WSZ;
    f16* Qph = (f16*)p; p += QSZ;
    f16* Qpl = (f16*)p; p += QSZ;
    f16* Kph = (f16*)p; p += KVSZ;
    f16* Kpl = (f16*)p; p += KVSZ;
    float* wAll = (float*)p; p += WALLS;

    // Separate VT buffer if workspace allows (enables single merged qkv launch);
    // else overlay dead kh/kl + wq/wk-hi (needs V-proj in a separate launch).
    size_t used = (size_t)(p - (char*)d_ws);
    bool sepVT = (ws_size >= used + 2 * VTSZ);
    f16 *VTh, *VTl;
    if (sepVT) {
        VTh = (f16*)p;
        VTl = VTh + (size_t)B_SZ * 384 * VT_LD;
    } else {
        VTh = kh;
        VTl = VTh + (size_t)B_SZ * 384 * VT_LD;
    }
    f16* oh = qh;                      // attn out over dead qh/ql
    f16* ol = ql;

    // 1) prep
    {
        int total = 4 * WELEM + 3 * C_DIM;
        prep_kernel<<<(total + 255) / 256, 256, 0, stream>>>(
            w_q, w_k, w_v, w_proj, conv_w, bn_g, bn_b, bn_m, bn_v, Wh, Wl, wAll);
    }

    // 2) fused conv (Q + K + V + cls)
    {
        dim3 gc(H_IN + 1, B_SZ);
        fused_conv_kernel<<<gc, 256, 0, stream>>>(x, wAll, qh, ql, kh, kl, vh, vl);
    }

    // 3) projections
    if (sepVT) {
        dim3 g(3, QT64 + 2 * KVT64);   // (3, 594) -- one launch, no aliasing
        qkv_proj_kernel<<<g, 256, 0, stream>>>(qh, ql, kh, kl, vh, vl, Wh, Wl,
                                               Qph, Qpl, Kph, Kpl, VTh, VTl);
    } else {
        dim3 g(3, QT64 + KVT64);       // Q+K only
        qkv_proj_kernel<<<g, 256, 0, stream>>>(qh, ql, kh, kl, vh, vl, Wh, Wl,
                                               Qph, Qpl, Kph, Kpl, VTh, VTl);
        dim3 gv(3, KVT64);             // V after Q+K complete (overlay now dead)
        v_proj_kernel<<<gv, 256, 0, stream>>>(vh, vl, Wh + 2 * WELEM, Wl + 2 * WELEM,
                                              VTh, VTl);
    }

    // 4) MFMA attention v4 -> oh/ol
    {
        dim3 ga((TQ + 63) / 64, NH, B_SZ);
        attn_mfma4<<<ga, 256, 0, stream>>>(Qph, Qpl, Kph, Kpl, VTh, VTl, oh, ol);
    }

    // 5) output projection + bias -> f32 out
    {
        dim3 gp(3, QT64);
        out_proj_kernel<<<gp, 256, 0, stream>>>(oh, ol, Wh + 3 * WELEM, Wl + 3 * WELEM,
                                                b_proj, out);
    }
}

// Round 12
// 289.473 us; speedup vs baseline: 1.1159x; 1.0220x over previous
//
#include <hip/hip_runtime.h>
#include <math.h>

#define B_SZ   32
#define C_DIM  384
#define H_IN   28
#define W_IN   28
#define TQ     785   // 1 + 28*28
#define TKV    197   // 1 + 14*14
#define NH     6
#define HD     64
#define SCALE_F 0.05103103630798287f       // 384^-0.5
#define SCALE_L2E (0.05103103630798287f * 1.4426950408889634f)  // fold log2(e)
#define BN_EPS_F 1e-5f

#define QROWS    25120        // B_SZ*TQ
#define KVROWS   6304         // B_SZ*TKV
#define QROWS_P  25216
#define KVROWS_P 6400
#define WELEM    147456       // 384*384
#define VT_LD    208          // V^T key stride (16B-aligned rows, >= 197)

#define QT64     394          // QROWS_P/64
#define KVT64    100          // KVROWS_P/64

typedef _Float16 f16;
typedef f16  f16x8 __attribute__((ext_vector_type(8)));
typedef f16  f16x4 __attribute__((ext_vector_type(4)));
typedef float f32x4 __attribute__((ext_vector_type(4)));

__device__ __forceinline__ void split16(float v, f16& h, f16& l) {
    h = (f16)v;
    l = (f16)(v - (float)h);
}

// async global->LDS DMA, 16 B per lane. HW writes at wave-uniform base +
// lane*16 -- every call site computes LDS offset == idx*16 (lane-stride 16 B).
__device__ __forceinline__ void cp16(void* lds, const void* g) {
    __builtin_amdgcn_global_load_lds(
        (const __attribute__((address_space(1))) unsigned int*)g,
        (__attribute__((address_space(3))) unsigned int*)lds, 16, 0, 0);
}

// XCD-sibling swizzle: 24-block groups; the 3 n0-siblings of one y-tile sit at
// ids {g*24+xcd, +8, +16} -> same XCD under round-robin id%8 placement, so the
// shared A-panel is L2-local. Returns false for pad blocks.
__device__ __forceinline__ bool swz(int id, int yMax, int& y, int& n0) {
    int g = id / 24, w = id - g * 24;
    y = g * 8 + (w & 7);
    n0 = (w >> 3) * 128;
    return y < yMax;
}

// ---------------- prep: weight decompose (+scale fold into w_q) + conv/BN fold --
__global__ __launch_bounds__(256) void prep_kernel(
    const float* __restrict__ wq, const float* __restrict__ wk,
    const float* __restrict__ wv, const float* __restrict__ wp,
    const float* __restrict__ conv_w,
    const float* __restrict__ gamma, const float* __restrict__ beta,
    const float* __restrict__ mean, const float* __restrict__ var,
    f16* __restrict__ Wh, f16* __restrict__ Wl,
    float* __restrict__ wAll)
{
    int idx = blockIdx.x * 256 + threadIdx.x;
    if (idx < 4 * WELEM) {
        int which = idx / WELEM, rem = idx - which * WELEM;
        const float* s = (which == 0) ? wq : (which == 1) ? wk : (which == 2) ? wv : wp;
        float v = s[rem];
        if (which == 0) v *= SCALE_L2E;   // QK^T logits in log2 domain
        f16 h, l;
        split16(v, h, l);
        Wh[idx] = h; Wl[idx] = l;
    } else if (idx < 4 * WELEM + 3 * C_DIM) {
        int k = idx - 4 * WELEM;
        int cv = k / C_DIM, c = k - cv * C_DIM;
        float inv = gamma[k] * rsqrtf(var[k] + BN_EPS_F);
#pragma unroll
        for (int t = 0; t < 9; ++t)
            wAll[cv * 3840 + t * C_DIM + c] = conv_w[(size_t)cv * C_DIM * 9 + c * 9 + t] * inv;
        wAll[cv * 3840 + 9 * C_DIM + c] = beta[k] - mean[k] * inv;
    }
}

// ---------------- fused depthwise conv (Q stride1 + K/V stride2) + cls row -----
__global__ __launch_bounds__(256) void fused_conv_kernel(
    const float* __restrict__ x,
    const float* __restrict__ wAll,
    f16* __restrict__ qh, f16* __restrict__ ql,
    f16* __restrict__ kh, f16* __restrict__ kl,
    f16* __restrict__ vh, f16* __restrict__ vl)
{
    __shared__ float sW[3 * 3840];
    int tid = threadIdx.x;
    int oi = blockIdx.x, b = blockIdx.y;

    if (oi == H_IN) {                 // cls-token path
        if (tid < 96) {
            int c = tid * 4;
            float4 v = *(const float4*)&x[(size_t)b * TQ * C_DIM + c];
            float a[4] = {v.x, v.y, v.z, v.w};
            f16x4 hv, lv;
#pragma unroll
            for (int u = 0; u < 4; ++u) { f16 h, l; split16(a[u], h, l); hv[u] = h; lv[u] = l; }
            size_t oq = (size_t)b * TQ * C_DIM + c;
            size_t okv = (size_t)b * TKV * C_DIM + c;
            *(f16x4*)&qh[oq] = hv;  *(f16x4*)&ql[oq] = lv;
            *(f16x4*)&kh[okv] = hv; *(f16x4*)&kl[okv] = lv;
            *(f16x4*)&vh[okv] = hv; *(f16x4*)&vl[okv] = lv;
        }
        return;
    }

#pragma unroll
    for (int i = 0; i < 12; ++i) {
        int idx = tid + 256 * i;
        if (idx < 2880) cp16(&sW[idx * 4], &wAll[idx * 4]);
    }
    __syncthreads();

    const size_t xb = (size_t)b * TQ * C_DIM + C_DIM;
    bool oi_even = (oi & 1) == 0;

    for (int it = 0; it < 11; ++it) {
        int idx = tid + 256 * it;
        if (idx >= 28 * 96) break;
        int oj = idx / 96, cg = idx - oj * 96;
        int c = cg * 4;

        float4 xv[9];
#pragma unroll
        for (int di = 0; di < 3; ++di) {
            int ii = oi + di - 1;
            bool rok = (ii >= 0) && (ii < H_IN);
#pragma unroll
            for (int dj = 0; dj < 3; ++dj) {
                int jj = oj + dj - 1;
                bool ok = rok && (jj >= 0) && (jj < W_IN);
                xv[di * 3 + dj] = ok ? *(const float4*)&x[xb + ((size_t)ii * W_IN + jj) * C_DIM + c]
                                     : make_float4(0.f, 0.f, 0.f, 0.f);
            }
        }

        {
            float4 acc = *(const float4*)&sW[0 * 3840 + 9 * C_DIM + c];
#pragma unroll
            for (int t = 0; t < 9; ++t) {
                float4 w4 = *(const float4*)&sW[0 * 3840 + t * C_DIM + c];
                acc.x += w4.x * xv[t].x; acc.y += w4.y * xv[t].y;
                acc.z += w4.z * xv[t].z; acc.w += w4.w * xv[t].w;
            }
            f16x4 hv, lv;
            float a[4] = {acc.x, acc.y, acc.z, acc.w};
#pragma unroll
            for (int u = 0; u < 4; ++u) { f16 h, l; split16(a[u], h, l); hv[u] = h; lv[u] = l; }
            size_t off = ((size_t)b * TQ + 1 + oi * W_IN + oj) * C_DIM + c;
            *(f16x4*)&qh[off] = hv;
            *(f16x4*)&ql[off] = lv;
        }

        if (oi_even && ((oj & 1) == 0)) {
            int p = (oi >> 1) * 14 + (oj >> 1);
            size_t off = ((size_t)b * TKV + 1 + p) * C_DIM + c;
#pragma unroll
            for (int cv = 1; cv <= 2; ++cv) {
                float4 acc = *(const float4*)&sW[cv * 3840 + 9 * C_DIM + c];
#pragma unroll
                for (int t = 0; t < 9; ++t) {
                    float4 w4 = *(const float4*)&sW[cv * 3840 + t * C_DIM + c];
                    acc.x += w4.x * xv[t].x; acc.y += w4.y * xv[t].y;
                    acc.z += w4.z * xv[t].z; acc.w += w4.w * xv[t].w;
                }
                f16x4 hv, lv;
                float a[4] = {acc.x, acc.y, acc.z, acc.w};
#pragma unroll
                for (int u = 0; u < 4; ++u) { f16 h, l; split16(a[u], h, l); hv[u] = h; lv[u] = l; }
                if (cv == 1) { *(f16x4*)&kh[off] = hv; *(f16x4*)&kl[off] = lv; }
                else         { *(f16x4*)&vh[off] = hv; *(f16x4*)&vl[off] = lv; }
            }
        }
    }
}

// ---------------- split-f16 MFMA GEMM body (64x128 tile, double-buffered DMA) --
// DMA(k+1) is issued immediately AFTER the barrier that drains DMA(k), so the
// next barrier's vmcnt(0) drain has had a full compute phase in flight.
// LDS 48 KB -> 3 blocks/CU. Staging offsets all == t*16 (lane-contiguous).
__device__ __forceinline__ void gemm_body(
    const f16* __restrict__ Ah, const f16* __restrict__ Al,
    const f16* __restrict__ Wh, const f16* __restrict__ Wl,
    const float* __restrict__ bias,
    float* __restrict__ Cf, f16* __restrict__ Coh, f16* __restrict__ Col,
    int M, int mode, int m0, int n0)
{
    __shared__ f16 sAh[2][64][32];
    __shared__ f16 sAl[2][64][32];
    __shared__ f16 sWh[2][128][32];
    __shared__ f16 sWl[2][128][32];

    int t = threadIdx.x;
    int wv = t >> 6, lane = t & 63;
    int wr = (wv >> 1) * 32, wc = (wv & 1) * 64;
    int lrow = lane & 15, quad = lane >> 4;
    int arow = t >> 2;
    int aseg = (t & 3) * 8;

    const f16* pAh = &Ah[(size_t)(m0 + arow) * 384 + aseg];
    const f16* pAl = &Al[(size_t)(m0 + arow) * 384 + aseg];
    const f16* pW0h = &Wh[(size_t)(n0 + arow) * 384 + aseg];
    const f16* pW1h = &Wh[(size_t)(n0 + arow + 64) * 384 + aseg];
    const f16* pW0l = &Wl[(size_t)(n0 + arow) * 384 + aseg];
    const f16* pW1l = &Wl[(size_t)(n0 + arow + 64) * 384 + aseg];

    f32x4 acc[2][4];
#pragma unroll
    for (int i = 0; i < 2; ++i)
#pragma unroll
        for (int j = 0; j < 4; ++j)
            acc[i][j] = (f32x4){0.f, 0.f, 0.f, 0.f};

    // prologue: DMA K-step 0 into buffer 0
    cp16(&sAh[0][arow][aseg],      pAh);
    cp16(&sAl[0][arow][aseg],      pAl);
    cp16(&sWh[0][arow][aseg],      pW0h);
    cp16(&sWh[0][arow + 64][aseg], pW1h);
    cp16(&sWl[0][arow][aseg],      pW0l);
    cp16(&sWl[0][arow + 64][aseg], pW1l);

    for (int kk = 0; kk < 12; ++kk) {
        __syncthreads();               // drains DMA(kk); prior reads of buf[(kk+1)&1] done
        if (kk < 11) {
            int bn = (kk + 1) & 1;
            int ko = (kk + 1) * 32;
            cp16(&sAh[bn][arow][aseg],      pAh + ko);
            cp16(&sAl[bn][arow][aseg],      pAl + ko);
            cp16(&sWh[bn][arow][aseg],      pW0h + ko);
            cp16(&sWh[bn][arow + 64][aseg], pW1h + ko);
            cp16(&sWl[bn][arow][aseg],      pW0l + ko);
            cp16(&sWl[bn][arow + 64][aseg], pW1l + ko);
        }
        int bc = kk & 1;

        f16x8 bh[4], bl[4];
#pragma unroll
        for (int j = 0; j < 4; ++j) {
            bh[j] = *(const f16x8*)&sWh[bc][wc + j * 16 + lrow][quad * 8];
            bl[j] = *(const f16x8*)&sWl[bc][wc + j * 16 + lrow][quad * 8];
        }
#pragma unroll
        for (int i = 0; i < 2; ++i) {
            f16x8 ah = *(const f16x8*)&sAh[bc][wr + i * 16 + lrow][quad * 8];
            f16x8 al = *(const f16x8*)&sAl[bc][wr + i * 16 + lrow][quad * 8];
#pragma unroll
            for (int j = 0; j < 4; ++j) {
                acc[i][j] = __builtin_amdgcn_mfma_f32_16x16x32_f16(ah, bh[j], acc[i][j], 0, 0, 0);
                acc[i][j] = __builtin_amdgcn_mfma_f32_16x16x32_f16(ah, bl[j], acc[i][j], 0, 0, 0);
                acc[i][j] = __builtin_amdgcn_mfma_f32_16x16x32_f16(al, bh[j], acc[i][j], 0, 0, 0);
            }
        }
    }

    // epilogue: C/D layout col=lane&15, row=quad*4+reg
#pragma unroll
    for (int i = 0; i < 2; ++i) {
        int grow0 = m0 + wr + i * 16 + quad * 4;
#pragma unroll
        for (int j = 0; j < 4; ++j) {
            int gcol = n0 + wc + j * 16 + lrow;
            float bb = (bias && mode == 0) ? bias[gcol] : 0.f;
#pragma unroll
            for (int r = 0; r < 4; ++r) {
                int grow = grow0 + r;
                if (grow >= M) continue;
                float v = acc[i][j][r] + bb;
                if (mode == 0) {
                    Cf[(size_t)grow * 384 + gcol] = v;
                } else if (mode == 1) {
                    f16 h, l;
                    split16(v, h, l);
                    Coh[(size_t)grow * 384 + gcol] = h;
                    Col[(size_t)grow * 384 + gcol] = l;
                } else {
                    int bb2 = grow / TKV;
                    int key = grow - bb2 * TKV;
                    size_t off = (size_t)bb2 * 384 * VT_LD + (size_t)gcol * VT_LD + key;
                    f16 h, l;
                    split16(v, h, l);
                    Coh[off] = h;
                    Col[off] = l;
                }
            }
        }
    }
}

// Q/K/V projections, swizzled 1-D grid. y in [0,394) Q, [394,494) K, [494,594) V.
__global__ __launch_bounds__(256) void qkv_proj_kernel(
    const f16* __restrict__ qh, const f16* __restrict__ ql,
    const f16* __restrict__ kh, const f16* __restrict__ kl,
    const f16* __restrict__ vh, const f16* __restrict__ vl,
    const f16* __restrict__ Wh, const f16* __restrict__ Wl,
    f16* __restrict__ Qph, f16* __restrict__ Qpl,
    f16* __restrict__ Kph, f16* __restrict__ Kpl,
    f16* __restrict__ VTh, f16* __restrict__ VTl,
    int yMax)
{
    int y, n0;
    if (!swz(blockIdx.x, yMax, y, n0)) return;
    if (y < QT64)
        gemm_body(qh, ql, Wh, Wl, nullptr, nullptr, Qph, Qpl, QROWS, 1, y * 64, n0);
    else if (y < QT64 + KVT64)
        gemm_body(kh, kl, Wh + WELEM, Wl + WELEM, nullptr, nullptr, Kph, Kpl,
                  KVROWS, 1, (y - QT64) * 64, n0);
    else
        gemm_body(vh, vl, Wh + 2 * WELEM, Wl + 2 * WELEM, nullptr, nullptr, VTh, VTl,
                  KVROWS, 2, (y - QT64 - KVT64) * 64, n0);
}

// fallback V projection (aliased-VT workspace layout), swizzled
__global__ __launch_bounds__(256) void v_proj_kernel(
    const f16* __restrict__ vh, const f16* __restrict__ vl,
    const f16* __restrict__ Wh, const f16* __restrict__ Wl,
    f16* __restrict__ VTh, f16* __restrict__ VTl)
{
    int y, n0;
    if (!swz(blockIdx.x, KVT64, y, n0)) return;
    gemm_body(vh, vl, Wh, Wl, nullptr, nullptr, VTh, VTl, KVROWS, 2, y * 64, n0);
}

__global__ __launch_bounds__(256) void out_proj_kernel(
    const f16* __restrict__ Ah, const f16* __restrict__ Al,
    const f16* __restrict__ Wh, const f16* __restrict__ Wl,
    const float* __restrict__ bias, float* __restrict__ Cf)
{
    int y, n0;
    if (!swz(blockIdx.x, QT64, y, n0)) return;
    gemm_body(Ah, Al, Wh, Wl, bias, Cf, nullptr, nullptr, QROWS, 0, y * 64, n0);
}

// ---------------- MFMA attention v4: single-pass softmax + hidden DMA ----------
__global__ __launch_bounds__(256) void attn_mfma4(
    const f16* __restrict__ Qh, const f16* __restrict__ Ql,
    const f16* __restrict__ Kh, const f16* __restrict__ Kl,
    const f16* __restrict__ VTh, const f16* __restrict__ VTl,
    f16* __restrict__ Oh, f16* __restrict__ Ol)
{
    __shared__ f16 sQh[2][64][32];
    __shared__ f16 sQl[2][64][32];
    __shared__ f16 sKh[2][64][32];
    __shared__ f16 sKl[2][64][32];
    __shared__ float sPs[64][68];

    int t = threadIdx.x;
    int wv = t >> 6, lane = t & 63;
    int c = lane & 15, quad = lane >> 4;
    int wq0 = wv * 16;
    int h = blockIdx.y, b = blockIdx.z;
    int q0 = blockIdx.x * 64;

    const size_t qbase  = (size_t)b * TQ * C_DIM + h * HD;
    const size_t kbase  = (size_t)b * TKV * C_DIM + h * HD;
    const size_t vtbase = (size_t)b * 384 * VT_LD + (size_t)h * HD * VT_LD;

#pragma unroll
    for (int i = 0; i < 2; ++i) {
        int idx = t + 256 * i;
        int ks = idx >> 8, row = (idx >> 2) & 63, sg = (idx & 3) * 8;
        cp16(&sQh[ks][row][sg], &Qh[qbase + (size_t)(q0 + row) * C_DIM + ks * 32 + sg]);
        cp16(&sQl[ks][row][sg], &Ql[qbase + (size_t)(q0 + row) * C_DIM + ks * 32 + sg]);
    }

    f32x4 s[4][4];
#pragma unroll
    for (int kt = 0; kt < 4; ++kt)
#pragma unroll
        for (int j = 0; j < 4; ++j)
            s[kt][j] = (f32x4){0.f, 0.f, 0.f, 0.f};

#pragma unroll
    for (int kt = 0; kt < 4; ++kt) {
        if (kt) __syncthreads();
#pragma unroll
        for (int i = 0; i < 2; ++i) {
            int idx = t + 256 * i;
            int ks = idx >> 8, row = (idx >> 2) & 63, sg = (idx & 3) * 8;
            cp16(&sKh[ks][row][sg], &Kh[kbase + (size_t)(kt * 64 + row) * C_DIM + ks * 32 + sg]);
            cp16(&sKl[ks][row][sg], &Kl[kbase + (size_t)(kt * 64 + row) * C_DIM + ks * 32 + sg]);
        }
        __syncthreads();

#pragma unroll
        for (int ks = 0; ks < 2; ++ks) {
            f16x8 qh8 = *(const f16x8*)&sQh[ks][wq0 + c][quad * 8];
            f16x8 ql8 = *(const f16x8*)&sQl[ks][wq0 + c][quad * 8];
#pragma unroll
            for (int j = 0; j < 4; ++j) {
                f16x8 kh8 = *(const f16x8*)&sKh[ks][j * 16 + c][quad * 8];
                f16x8 kl8 = *(const f16x8*)&sKl[ks][j * 16 + c][quad * 8];
                s[kt][j] = __builtin_amdgcn_mfma_f32_16x16x32_f16(qh8, kh8, s[kt][j], 0, 0, 0);
                s[kt][j] = __builtin_amdgcn_mfma_f32_16x16x32_f16(qh8, kl8, s[kt][j], 0, 0, 0);
                s[kt][j] = __builtin_amdgcn_mfma_f32_16x16x32_f16(ql8, kh8, s[kt][j], 0, 0, 0);
            }
        }
    }

    __syncthreads();                   // all S frag reads done: K panels free

    // VT tile 0 DMA rides under the softmax VALU
#pragma unroll
    for (int i = 0; i < 2; ++i) {
        int idx = t + 256 * i;
        int ks = idx >> 8, row = (idx >> 2) & 63, sg = (idx & 3) * 8;
        cp16(&sKh[ks][row][sg], &VTh[vtbase + (size_t)row * VT_LD + ks * 32 + sg]);
        cp16(&sKl[ks][row][sg], &VTl[vtbase + (size_t)row * VT_LD + ks * 32 + sg]);
    }

#pragma unroll
    for (int r = 0; r < 4; ++r) {
        s[3][0][r] = (c < 5) ? s[3][0][r] : -1e30f;
        s[3][1][r] = -1e30f;
        s[3][2][r] = -1e30f;
        s[3][3][r] = -1e30f;
    }

    float inv_r[4];
#pragma unroll
    for (int r = 0; r < 4; ++r) {
        float mx = -1e30f;
#pragma unroll
        for (int kt = 0; kt < 4; ++kt)
#pragma unroll
            for (int j = 0; j < 4; ++j)
                mx = fmaxf(mx, s[kt][j][r]);
        mx = fmaxf(mx, __shfl_xor(mx, 1));
        mx = fmaxf(mx, __shfl_xor(mx, 2));
        mx = fmaxf(mx, __shfl_xor(mx, 4));
        mx = fmaxf(mx, __shfl_xor(mx, 8));
        float sum = 0.f;
#pragma unroll
        for (int kt = 0; kt < 4; ++kt)
#pragma unroll
            for (int j = 0; j < 4; ++j) {
                float pv = exp2f(s[kt][j][r] - mx);
                s[kt][j][r] = pv;
                sum += pv;
            }
        sum += __shfl_xor(sum, 1);
        sum += __shfl_xor(sum, 2);
        sum += __shfl_xor(sum, 4);
        sum += __shfl_xor(sum, 8);
        inv_r[r] = 1.f / sum;
    }

    f32x4 o[4];
#pragma unroll
    for (int j = 0; j < 4; ++j) o[j] = (f32x4){0.f, 0.f, 0.f, 0.f};

#pragma unroll
    for (int vt = 0; vt < 4; ++vt) {
#pragma unroll
        for (int r = 0; r < 4; ++r)
#pragma unroll
            for (int j = 0; j < 4; ++j)
                sPs[wq0 + quad * 4 + r][j * 16 + c] = s[vt][j][r];

        __syncthreads();               // drains DMA(vt); sPs visible

#pragma unroll
        for (int ks = 0; ks < 2; ++ks) {
            float4 p0 = *(const float4*)&sPs[wq0 + c][ks * 32 + quad * 8];
            float4 p1 = *(const float4*)&sPs[wq0 + c][ks * 32 + quad * 8 + 4];
            float pf[8] = {p0.x, p0.y, p0.z, p0.w, p1.x, p1.y, p1.z, p1.w};
            f16x8 ph8, pl8;
#pragma unroll
            for (int ii = 0; ii < 8; ++ii) {
                f16 hh, ll;
                split16(pf[ii], hh, ll);
                ph8[ii] = hh; pl8[ii] = ll;
            }
#pragma unroll
            for (int j = 0; j < 4; ++j) {
                f16x8 vh8 = *(const f16x8*)&sKh[ks][j * 16 + c][quad * 8];
                f16x8 vl8 = *(const f16x8*)&sKl[ks][j * 16 + c][quad * 8];
                o[j] = __builtin_amdgcn_mfma_f32_16x16x32_f16(ph8, vh8, o[j], 0, 0, 0);
                o[j] = __builtin_amdgcn_mfma_f32_16x16x32_f16(ph8, vl8, o[j], 0, 0, 0);
                o[j] = __builtin_amdgcn_mfma_f32_16x16x32_f16(pl8, vh8, o[j], 0, 0, 0);
            }
        }

        if (vt < 3) {
            __syncthreads();
#pragma unroll
            for (int i = 0; i < 2; ++i) {
                int idx = t + 256 * i;
                int ks = idx >> 8, row = (idx >> 2) & 63, sg = (idx & 3) * 8;
                cp16(&sKh[ks][row][sg],
                     &VTh[vtbase + (size_t)row * VT_LD + (vt + 1) * 64 + ks * 32 + sg]);
                cp16(&sKl[ks][row][sg],
                     &VTl[vtbase + (size_t)row * VT_LD + (vt + 1) * 64 + ks * 32 + sg]);
            }
        }
    }

#pragma unroll
    for (int r = 0; r < 4; ++r) {
        int gq = q0 + wq0 + quad * 4 + r;
        if (gq >= TQ) continue;
        float inv = inv_r[r];
#pragma unroll
        for (int j = 0; j < 4; ++j) {
            float v = o[j][r] * inv;
            f16 hh, ll;
            split16(v, hh, ll);
            size_t off = (size_t)(b * TQ + gq) * C_DIM + h * HD + j * 16 + c;
            Oh[off] = hh;
            Ol[off] = ll;
        }
    }
}

extern "C" void kernel_launch(void* const* d_in, const int* in_sizes, int n_in,
                              void* d_out, int out_size, void* d_ws, size_t ws_size,
                              hipStream_t stream) {
    const float* x       = (const float*)d_in[0];
    const float* conv_w  = (const float*)d_in[1];
    const float* bn_g    = (const float*)d_in[2];
    const float* bn_b    = (const float*)d_in[3];
    const float* bn_m    = (const float*)d_in[4];
    const float* bn_v    = (const float*)d_in[5];
    const float* w_q     = (const float*)d_in[6];
    const float* w_k     = (const float*)d_in[7];
    const float* w_v     = (const float*)d_in[8];
    const float* w_proj  = (const float*)d_in[9];
    const float* b_proj  = (const float*)d_in[10];
    float* out = (float*)d_out;

    const size_t QSZ   = (size_t)QROWS_P * 384 * sizeof(f16);
    const size_t KVSZ  = (size_t)KVROWS_P * 384 * sizeof(f16);
    const size_t WSZ   = 4 * (size_t)WELEM * sizeof(f16);
    const size_t VTSZ  = (size_t)B_SZ * 384 * VT_LD * sizeof(f16);
    const size_t WALLS = 3 * 3840 * sizeof(float);

    char* p = (char*)d_ws;
    f16* qh  = (f16*)p; p += QSZ;
    f16* ql  = (f16*)p; p += QSZ;
    f16* vh  = (f16*)p; p += KVSZ;
    f16* vl  = (f16*)p; p += KVSZ;
    f16* kh  = (f16*)p; p += KVSZ;
    f16* kl  = (f16*)p; p += KVSZ;
    f16* Wh  = (f16*)p; p += WSZ;
    f16* Wl  = (f16*)p; p += WSZ;
    f16* Qph = (f16*)p; p += QSZ;
    f16* Qpl = (f16*)p; p += QSZ;
    f16* Kph = (f16*)p; p += KVSZ;
    f16* Kpl = (f16*)p; p += KVSZ;
    float* wAll = (float*)p; p += WALLS;

    size_t used = (size_t)(p - (char*)d_ws);
    bool sepVT = (ws_size >= used + 2 * VTSZ);
    f16 *VTh, *VTl;
    if (sepVT) {
        VTh = (f16*)p;
        VTl = VTh + (size_t)B_SZ * 384 * VT_LD;
    } else {
        VTh = kh;
        VTl = VTh + (size_t)B_SZ * 384 * VT_LD;
    }
    f16* oh = qh;
    f16* ol = ql;

    // 1) prep
    {
        int total = 4 * WELEM + 3 * C_DIM;
        prep_kernel<<<(total + 255) / 256, 256, 0, stream>>>(
            w_q, w_k, w_v, w_proj, conv_w, bn_g, bn_b, bn_m, bn_v, Wh, Wl, wAll);
    }

    // 2) fused conv (Q + K + V + cls)
    {
        dim3 gc(H_IN + 1, B_SZ);
        fused_conv_kernel<<<gc, 256, 0, stream>>>(x, wAll, qh, ql, kh, kl, vh, vl);
    }

    // 3) projections (swizzled 1-D grids; blocks = ceil(yMax/8)*24)
    if (sepVT) {
        int yMax = QT64 + 2 * KVT64;               // 594
        int nb = ((yMax + 7) / 8) * 24;            // 1800
        qkv_proj_kernel<<<nb, 256, 0, stream>>>(qh, ql, kh, kl, vh, vl, Wh, Wl,
                                                Qph, Qpl, Kph, Kpl, VTh, VTl, yMax);
    } else {
        int yMax = QT64 + KVT64;                   // 494
        int nb = ((yMax + 7) / 8) * 24;            // 1488
        qkv_proj_kernel<<<nb, 256, 0, stream>>>(qh, ql, kh, kl, vh, vl, Wh, Wl,
                                                Qph, Qpl, Kph, Kpl, VTh, VTl, yMax);
        int nbv = ((KVT64 + 7) / 8) * 24;          // 312
        v_proj_kernel<<<nbv, 256, 0, stream>>>(vh, vl, Wh + 2 * WELEM, Wl + 2 * WELEM,
                                               VTh, VTl);
    }

    // 4) MFMA attention v4 -> oh/ol
    {
        dim3 ga((TQ + 63) / 64, NH, B_SZ);
        attn_mfma4<<<ga, 256, 0, stream>>>(Qph, Qpl, Kph, Kpl, VTh, VTl, oh, ol);
    }

    // 5) output projection + bias -> f32 out
    {
        int nb = ((QT64 + 7) / 8) * 24;            // 1200
        out_proj_kernel<<<nb, 256, 0, stream>>>(oh, ol, Wh + 3 * WELEM, Wl + 3 * WELEM,
                                                b_proj, out);
    }
}